// Round 17
// baseline (259.906 us; speedup 1.0000x reference)
//
#include <hip/hip_runtime.h>
#include <hip/hip_cooperative_groups.h>
namespace cg = cooperative_groups;

#define BATCH 4096
#define MD 384
#define KW 15
#define LSEQ 28
#define FIN 28
#define NX (BATCH*LSEQ*FIN)
#define NROWS (BATCH*LSEQ)
#define NTILE 1024

// workspace layout (byte offsets, 16B-aligned)
#define B_PT0  1024      // <=512 float4
#define B_PT1  33792     // <=512 float2
#define B_PT2  50176     // <=512 float2
#define B_PTL  66560     // <=512 float
#define B_W1B  74752     // MD*32 bf16 = 24576
#define B_WCQ  99328     // MD*16 i8 = 6144
#define B_WFB  105472    // 16*10752 i8 = 172032 (rows 10..15 pad)
#define B_LG   277504    // 40960 float
#define B_XQB  441344    // NROWS*32 bf16 = 7340032
#define B_CWG  7781376   // 1024 tiles * 10752 ints

typedef __bf16 bf16x8 __attribute__((ext_vector_type(8)));
typedef float f32x4 __attribute__((ext_vector_type(4)));
typedef int i32x4 __attribute__((ext_vector_type(4)));

#if __has_builtin(__builtin_amdgcn_sdot4)
#define SDOT4(a,b,c) __builtin_amdgcn_sdot4((a),(b),(c),false)
#else
__device__ __forceinline__ int SDOT4(int a,int b,int c){
  c += ((a<<24)>>24)*((b<<24)>>24);
  c += ((a<<16)>>24)*((b<<16)>>24);
  c += ((a<<8)>>24)*((b<<8)>>24);
  c += (a>>24)*(b>>24);
  return c;
}
#endif

#if __has_builtin(__builtin_amdgcn_alignbyte)
#define ALIGNB(hi,lo,s) __builtin_amdgcn_alignbyte((hi),(lo),(s))
#else
#define ALIGNB(hi,lo,s) ((int)(((unsigned)(lo)>>(8*(s)))|((unsigned)(hi)<<(32-8*(s)))))
#endif

__device__ __forceinline__ unsigned short f2bf(float f){
  return (unsigned short)(__float_as_uint(f)>>16);   // exact for small ints
}
__device__ __forceinline__ unsigned lut_bperm(int iw,int lutw){
  int res=__builtin_amdgcn_ds_bpermute(iw,lutw);    // lane = iw>>2
  return ((unsigned)res>>(8*(iw&3)))&0xFFu;
}

#define CWS 29          // padded Cw row stride (ints), coprime with 32
#define DWS 2692        // Dw sample stride in INTS (2688 data + 4 pad)

__global__ __launch_bounds__(512,4)
void k_mega(const float* __restrict__ img,const float* __restrict__ W1v,
            const float* __restrict__ b1,const float* __restrict__ Wc,
            const float* __restrict__ bc,const float* __restrict__ Wf,
            const float* __restrict__ bfv,float* __restrict__ out,
            char* __restrict__ wsb,int nblk){
  cg::grid_group grid=cg::this_grid();
  __shared__ int ldsI[MD*CWS];
  __shared__ int psumN[8][10][4];
  __shared__ char lutA[256];
  __shared__ char lutB[256];
  __shared__ float sred[8][4];
  __shared__ float bsv[9];  // s_img,s_w1,s_wc,s_wf,s_lin,s_o1,s_cv,s_o2,s_log

  int t=threadIdx.x, bid=blockIdx.x;
  int wid=t>>6, lane=t&63, l4=lane>>4, l15=lane&15;

  float4* pt0=(float4*)(wsb+B_PT0);
  float2* pt1=(float2*)(wsb+B_PT1);
  float2* pt2=(float2*)(wsb+B_PT2);
  float* ptl=(float*)(wsb+B_PTL);
  float* lg=(float*)(wsb+B_LG);
  int* cwg=(int*)(wsb+B_CWG);
  unsigned short* xqb=(unsigned short*)(wsb+B_XQB);
  unsigned short* w1b=(unsigned short*)(wsb+B_W1B);
  char* wcpk=wsb+B_WCQ;
  char* wfb=wsb+B_WFB;

  // ---------- P1: maxabs over inputs ----------
  {
    float m0=0.f,m1=0.f,m2=0.f,m3=0.f;
    const int N4=NX/4;
    const int NW1=MD*FIN,NWC=MD*KW,NWF=10*MD*LSEQ;
    const int total=N4+NW1+NWC+NWF;
    const float4* img4=(const float4*)img;
    for(int i=bid*512+t;i<total;i+=nblk*512){
      if(i<N4){
        float4 v=img4[i];
        m0=fmaxf(m0,fmaxf(fmaxf(fabsf(v.x),fabsf(v.y)),fmaxf(fabsf(v.z),fabsf(v.w))));
      }
      else if(i<N4+NW1) m1=fmaxf(m1,fabsf(W1v[i-N4]));
      else if(i<N4+NW1+NWC) m2=fmaxf(m2,fabsf(Wc[i-N4-NW1]));
      else m3=fmaxf(m3,fabsf(Wf[i-N4-NW1-NWC]));
    }
    #pragma unroll
    for(int off=32;off;off>>=1){
      m0=fmaxf(m0,__shfl_xor(m0,off,64));
      m1=fmaxf(m1,__shfl_xor(m1,off,64));
      m2=fmaxf(m2,__shfl_xor(m2,off,64));
      m3=fmaxf(m3,__shfl_xor(m3,off,64));
    }
    if(lane==0){sred[wid][0]=m0;sred[wid][1]=m1;sred[wid][2]=m2;sred[wid][3]=m3;}
    __syncthreads();
    if(t==0){
      for(int i=1;i<8;i++){
        m0=fmaxf(m0,sred[i][0]);m1=fmaxf(m1,sred[i][1]);
        m2=fmaxf(m2,sred[i][2]);m3=fmaxf(m3,sred[i][3]);
      }
      pt0[bid]=make_float4(m0,m1,m2,m3);
    }
    __syncthreads();
  }
  grid.sync();
  // ---------- P1b: every block derives input scales ----------
  {
    float m0=0.f,m1=0.f,m2=0.f,m3=0.f;
    for(int i=t;i<nblk;i+=512){
      float4 v=pt0[i];
      m0=fmaxf(m0,v.x);m1=fmaxf(m1,v.y);m2=fmaxf(m2,v.z);m3=fmaxf(m3,v.w);
    }
    #pragma unroll
    for(int off=32;off;off>>=1){
      m0=fmaxf(m0,__shfl_xor(m0,off,64));
      m1=fmaxf(m1,__shfl_xor(m1,off,64));
      m2=fmaxf(m2,__shfl_xor(m2,off,64));
      m3=fmaxf(m3,__shfl_xor(m3,off,64));
    }
    if(lane==0){sred[wid][0]=m0;sred[wid][1]=m1;sred[wid][2]=m2;sred[wid][3]=m3;}
    __syncthreads();
    if(t==0){
      for(int i=1;i<8;i++){
        m0=fmaxf(m0,sred[i][0]);m1=fmaxf(m1,sred[i][1]);
        m2=fmaxf(m2,sred[i][2]);m3=fmaxf(m3,sred[i][3]);
      }
      bsv[0]=fmaxf(m0/127.f,1e-8f);
      bsv[1]=fmaxf(m1/3.f,1e-8f);
      bsv[2]=fmaxf(m2/3.f,1e-8f);
      bsv[3]=fmaxf(m3/3.f,1e-8f);
    }
    __syncthreads();
  }
  // ---------- P2: quantize inputs into code tensors ----------
  {
    float s_img=bsv[0],s_w1=bsv[1],s_wc=bsv[2],s_wf=bsv[3];
    float inv_img=1.f/s_img;
    const int T0=NROWS*32;
    const int T1=T0+MD*32;
    const int T2=T1+MD*16;
    const int T3=T2+10*10752;
    for(int i=bid*512+t;i<T3;i+=nblk*512){
      if(i<T0){
        int row=i>>5, cc=i&31;
        float q = cc<FIN ? fminf(fmaxf(rintf(img[row*FIN+cc]*inv_img),-128.f),127.f) : 0.f;
        xqb[i]=f2bf(q);
      } else if(i<T1){
        int j=i-T0; int o=j>>5, cc=j&31;
        float q = cc<FIN ? fminf(fmaxf(rintf(W1v[o*FIN+cc]/s_w1),-4.f),3.f) : 0.f;
        w1b[j]=f2bf(q);
      } else if(i<T2){
        int j=i-T1; int c=j>>4, k=j&15;
        char q=0;
        if(k<KW) q=(char)(int)fminf(fmaxf(rintf(Wc[c*KW+k]/s_wc),-4.f),3.f);
        wcpk[j]=q;
      } else {
        int j=i-T2;                 // wfb[n][c*28+l]
        int n=j/10752, r=j-n*10752;
        int c=r/28, l=r-c*28;
        wfb[j]=(char)(int)fminf(fmaxf(rintf(Wf[n*10752+l*MD+c]/s_wf),-4.f),3.f);
      }
    }
  }
  grid.sync();

  // ---------- P3: lin minmax (W1 frags staged once, kept in regs) ----------
  bf16x8 bfr[3]; float b1v[3];
  {
    const int* src=(const int*)w1b;
    for(int i=t;i<6144;i+=512) ldsI[i]=src[i];
    __syncthreads();
    unsigned short* Wlds=(unsigned short*)ldsI;
    #pragma unroll
    for(int ni=0;ni<3;ni++){
      int o=(wid*3+ni)*16+l15;
      bfr[ni]=*(const bf16x8*)&Wlds[o*32+l4*8];
      b1v[ni]=b1[o];
    }
    float sg=bsv[0]*bsv[1];
    f32x4 zero={0.f,0.f,0.f,0.f};
    float mnn[3]={1e30f,1e30f,1e30f},mxx[3]={-1e30f,-1e30f,-1e30f};
    for(int tile=bid;tile<NTILE;tile+=nblk){
      bf16x8 af[7];
      int r0=tile*112;
      #pragma unroll
      for(int mt=0;mt<7;mt++)
        af[mt]=*(const bf16x8*)&xqb[(size_t)(r0+mt*16+l15)*32+l4*8];
      #pragma unroll
      for(int ni=0;ni<3;ni++){
        #pragma unroll
        for(int mt=0;mt<7;mt++){
          f32x4 acc=__builtin_amdgcn_mfma_f32_16x16x32_bf16(af[mt],bfr[ni],zero,0,0,0);
          #pragma unroll
          for(int r=0;r<4;r++){
            mnn[ni]=fminf(mnn[ni],acc[r]); mxx[ni]=fmaxf(mxx[ni],acc[r]);
          }
        }
      }
    }
    float mn=1e30f,mx=-1e30f;
    #pragma unroll
    for(int ni=0;ni<3;ni++){
      mn=fminf(mn,fmaf(mnn[ni],sg,b1v[ni]));
      mx=fmaxf(mx,fmaf(mxx[ni],sg,b1v[ni]));
    }
    #pragma unroll
    for(int off=32;off;off>>=1){
      mn=fminf(mn,__shfl_xor(mn,off,64));
      mx=fmaxf(mx,__shfl_xor(mx,off,64));
    }
    if(lane==0){sred[wid][0]=mn;sred[wid][1]=mx;}
    __syncthreads();
    if(t==0){
      for(int i=1;i<8;i++){mn=fminf(mn,sred[i][0]);mx=fmaxf(mx,sred[i][1]);}
      pt1[bid]=make_float2(mn,mx);
    }
    __syncthreads();
  }
  grid.sync();
  // ---------- P3b: derive s_lin/s_o1 + LUT1 ----------
  {
    float mn=1e30f,mx=-1e30f;
    for(int i=t;i<nblk;i+=512){
      float2 v=pt1[i]; mn=fminf(mn,v.x); mx=fmaxf(mx,v.y);
    }
    #pragma unroll
    for(int off=32;off;off>>=1){
      mn=fminf(mn,__shfl_xor(mn,off,64));
      mx=fmaxf(mx,__shfl_xor(mx,off,64));
    }
    if(lane==0){sred[wid][0]=mn;sred[wid][1]=mx;}
    __syncthreads();
    if(t==0){
      for(int i=1;i<8;i++){mn=fminf(mn,sred[i][0]);mx=fmaxf(mx,sred[i][1]);}
      float ma=fmaxf(fabsf(mn),fabsf(mx));
      float s=fmaxf(ma/127.f,1e-8f);
      float a1=fabsf(fminf(fmaxf(rintf(mn/s),-128.f),127.f)*s);
      float a2=fabsf(fminf(fmaxf(rintf(mx/s),-128.f),127.f)*s);
      bsv[4]=s;
      bsv[5]=fmaxf(tanhf(fmaxf(a1,a2))/127.f,1e-8f);
    }
    __syncthreads();
    if(t<256){
      float d=(float)(t-128)*bsv[4];
      lutA[t]=(char)(int)fminf(fmaxf(rintf(tanhf(d)/bsv[5]),-128.f),127.f);
    }
    __syncthreads();
  }

  // ---------- P4: lin codes -> cwg dump + conv minmax ----------
  {
    float sg=bsv[0]*bsv[1];
    float inv_lin=1.f/bsv[4];
    float sgi=sg*inv_lin;
    float b1s[3];
    #pragma unroll
    for(int ni=0;ni<3;ni++) b1s[ni]=fmaf(b1v[ni],inv_lin,128.f);
    int lutA_w=((const int*)lutA)[lane];
    float sfac=bsv[5]*bsv[2];
    f32x4 zero={0.f,0.f,0.f,0.f};
    float mnc=1e30f,mxc=-1e30f;
    for(int tile=bid;tile<NTILE;tile+=nblk){
      __syncthreads();                 // prior tile's Cw reads complete
      bf16x8 af[7];
      int r0=tile*112;
      #pragma unroll
      for(int mt=0;mt<7;mt++)
        af[mt]=*(const bf16x8*)&xqb[(size_t)(r0+mt*16+l15)*32+l4*8];
      #pragma unroll
      for(int ni=0;ni<3;ni++){
        int o=(wid*3+ni)*16+l15;
        #pragma unroll
        for(int mt=0;mt<7;mt++){
          f32x4 acc=__builtin_amdgcn_mfma_f32_16x16x32_bf16(af[mt],bfr[ni],zero,0,0,0);
          unsigned w=0;
          #pragma unroll
          for(int r=0;r<4;r++){
            float x=fmaf(acc[r],sgi,b1s[ni]);
            int iw=(int)__builtin_amdgcn_fmed3f(rintf(x),0.f,255.f);
            w|=lut_bperm(iw,lutA_w)<<(8*r);
          }
          ldsI[o*CWS+mt*4+l4]=(int)w;
        }
      }
      __syncthreads();
      // dump Cw codes to cwg (coalesced int4)
      {
        int4* dst=(int4*)(cwg+(size_t)tile*10752);
        for(int jj=t;jj<2688;jj+=512){
          int j=jj*4, o=j/28, idx=j-o*28, base=o*CWS+idx;
          int4 v; v.x=ldsI[base]; v.y=ldsI[base+1]; v.z=ldsI[base+2]; v.w=ldsI[base+3];
          dst[jj]=v;
        }
      }
      // conv minmax: 1536 rows, 3/thread
      #pragma unroll
      for(int rr=0;rr<3;rr++){
        int j=t+rr*512;
        int s=j/384, c=j-s*384;
        i32x4 wq=*(const i32x4*)(wcpk+(size_t)c*16);
        float cbias=bc[c];
        int ext[11];
        ext[0]=0; ext[1]=0; ext[9]=0; ext[10]=0;
        #pragma unroll
        for(int i=0;i<7;i++) ext[2+i]=ldsI[c*CWS+s*7+i];
        int imn=0x7FFFFFFF,imx=0x80000000;
        #pragma unroll
        for(int l=0;l<LSEQ;l++){
          const int eb=l+1, bi=eb>>2, sh=eb&3;
          int A0,A1,A2,A3;
          if(sh==0){A0=ext[bi];A1=ext[bi+1];A2=ext[bi+2];A3=ext[bi+3];}
          else{
            A0=ALIGNB(ext[bi+1],ext[bi],sh);
            A1=ALIGNB(ext[bi+2],ext[bi+1],sh);
            A2=ALIGNB(ext[bi+3],ext[bi+2],sh);
            A3=ALIGNB(ext[bi+4],ext[bi+3],sh);
          }
          int idot=SDOT4(A0,wq[0],SDOT4(A1,wq[1],SDOT4(A2,wq[2],SDOT4(A3,wq[3],0))));
          imn=min(imn,idot); imx=max(imx,idot);
        }
        mnc=fminf(mnc,fmaf((float)imn,sfac,cbias));
        mxc=fmaxf(mxc,fmaf((float)imx,sfac,cbias));
      }
    }
    #pragma unroll
    for(int off=32;off;off>>=1){
      mnc=fminf(mnc,__shfl_xor(mnc,off,64));
      mxc=fmaxf(mxc,__shfl_xor(mxc,off,64));
    }
    __syncthreads();
    if(lane==0){sred[wid][0]=mnc;sred[wid][1]=mxc;}
    __syncthreads();
    if(t==0){
      for(int i=1;i<8;i++){mnc=fminf(mnc,sred[i][0]);mxc=fmaxf(mxc,sred[i][1]);}
      pt2[bid]=make_float2(mnc,mxc);
    }
    __syncthreads();
  }
  grid.sync();
  // ---------- P4b: derive s_cv/s_o2 + LUT2 ----------
  {
    float mn=1e30f,mx=-1e30f;
    for(int i=t;i<nblk;i+=512){
      float2 v=pt2[i]; mn=fminf(mn,v.x); mx=fmaxf(mx,v.y);
    }
    #pragma unroll
    for(int off=32;off;off>>=1){
      mn=fminf(mn,__shfl_xor(mn,off,64));
      mx=fmaxf(mx,__shfl_xor(mx,off,64));
    }
    if(lane==0){sred[wid][0]=mn;sred[wid][1]=mx;}
    __syncthreads();
    if(t==0){
      for(int i=1;i<8;i++){mn=fminf(mn,sred[i][0]);mx=fmaxf(mx,sred[i][1]);}
      float ma=fmaxf(fabsf(mn),fabsf(mx));
      float s=fmaxf(ma/127.f,1e-8f);
      float a1=fabsf(fminf(fmaxf(rintf(mn/s),-128.f),127.f)*s);
      float a2=fabsf(fminf(fmaxf(rintf(mx/s),-128.f),127.f)*s);
      bsv[6]=s;
      bsv[7]=fmaxf(tanhf(fmaxf(a1,a2))/127.f,1e-8f);
    }
    __syncthreads();
    if(t<256){
      float d=(float)(t-128)*bsv[6];
      lutB[t]=(char)(int)fminf(fmaxf(rintf(tanhf(d)/bsv[7]),-128.f),127.f);
    }
    __syncthreads();
  }

  // ---------- P5: conv codes -> Dw -> i8-MFMA gemm2 -> logits ----------
  {
    float inv_cv=1.f/bsv[6];
    float ck1=bsv[5]*bsv[2]*inv_cv;
    float gsc=bsv[3]*bsv[7];
    int lutB_w=((const int*)lutB)[lane];
    float mL=0.f;
    for(int tile=bid;tile<NTILE;tile+=nblk){
      __syncthreads();                 // prior tile reads complete
      {
        const int4* src=(const int4*)(cwg+(size_t)tile*10752);
        for(int jj=t;jj<2688;jj+=512){
          int4 v=src[jj];
          int j=jj*4, o=j/28, idx=j-o*28, base=o*CWS+idx;
          ldsI[base]=v.x; ldsI[base+1]=v.y; ldsI[base+2]=v.z; ldsI[base+3]=v.w;
        }
      }
      __syncthreads();
      int oww[3][7];
      #pragma unroll
      for(int rr=0;rr<3;rr++){
        int j=t+rr*512;
        int s=j/384, c=j-s*384;
        i32x4 wq=*(const i32x4*)(wcpk+(size_t)c*16);
        float cq2=fmaf(bc[c],inv_cv,128.f);
        int ext[11];
        ext[0]=0; ext[1]=0; ext[9]=0; ext[10]=0;
        #pragma unroll
        for(int i=0;i<7;i++) ext[2+i]=ldsI[c*CWS+s*7+i];
        #pragma unroll
        for(int l=0;l<LSEQ;l++){
          const int eb=l+1, bi=eb>>2, sh=eb&3;
          int A0,A1,A2,A3;
          if(sh==0){A0=ext[bi];A1=ext[bi+1];A2=ext[bi+2];A3=ext[bi+3];}
          else{
            A0=ALIGNB(ext[bi+1],ext[bi],sh);
            A1=ALIGNB(ext[bi+2],ext[bi+1],sh);
            A2=ALIGNB(ext[bi+3],ext[bi+2],sh);
            A3=ALIGNB(ext[bi+4],ext[bi+3],sh);
          }
          int idot=SDOT4(A0,wq[0],SDOT4(A1,wq[1],SDOT4(A2,wq[2],SDOT4(A3,wq[3],0))));
          float x=fmaf((float)idot,ck1,cq2);
          int iw=(int)__builtin_amdgcn_fmed3f(rintf(x),0.f,255.f);
          unsigned q2=lut_bperm(iw,lutB_w);
          if((l&3)==0) oww[rr][l>>2]=(int)q2;
          else oww[rr][l>>2]|=(int)(q2<<(8*(l&3)));
        }
      }
      __syncthreads();                 // all Cw reads done before Dw overwrite
      #pragma unroll
      for(int rr=0;rr<3;rr++){
        int j=t+rr*512;
        int s=j/384, c=j-s*384;
        #pragma unroll
        for(int i=0;i<7;i++) ldsI[s*DWS+c*7+i]=oww[rr][i];
      }
      __syncthreads();
      {
        i32x4 acc0={0,0,0,0}, acc1={0,0,0,0};
        const char* ldsB=(const char*)ldsI;
        for(int kb=wid;kb<168;kb+=16){
          i32x4 a=*(const i32x4*)(ldsB+(size_t)(l15&3)*(DWS*4)+kb*64+l4*16);
          i32x4 b=*(const i32x4*)(wfb+(size_t)l15*10752+kb*64+l4*16);
          acc0=__builtin_amdgcn_mfma_i32_16x16x64_i8(a,b,acc0,0,0,0);
          int kb2=kb+8;
          if(kb2<168){
            i32x4 a2=*(const i32x4*)(ldsB+(size_t)(l15&3)*(DWS*4)+kb2*64+l4*16);
            i32x4 b2=*(const i32x4*)(wfb+(size_t)l15*10752+kb2*64+l4*16);
            acc1=__builtin_amdgcn_mfma_i32_16x16x64_i8(a2,b2,acc1,0,0,0);
          }
        }
        if(l4==0&&l15<10){
          #pragma unroll
          for(int r=0;r<4;r++) psumN[wid][l15][r]=acc0[r]+acc1[r];
        }
      }
      __syncthreads();
      float m=0.f;
      if(t<40){
        int s=t/10, o=t-s*10;
        int sum=0;
        #pragma unroll
        for(int w=0;w<8;w++) sum+=psumN[w][o][s];
        float v=fmaf((float)sum,gsc,bfv[o]);
        lg[(size_t)tile*40+t]=v;
        m=fabsf(v);
      }
      if(t<64){
        #pragma unroll
        for(int off=32;off;off>>=1) m=fmaxf(m,__shfl_xor(m,off,64));
        if(t==0) mL=fmaxf(mL,m);
      }
    }
    if(t==0) ptl[bid]=mL;
    __syncthreads();
  }
  grid.sync();
  // ---------- P6: final quantize ----------
  {
    float m=0.f;
    for(int i=t;i<nblk;i+=512) m=fmaxf(m,ptl[i]);
    #pragma unroll
    for(int off=32;off;off>>=1) m=fmaxf(m,__shfl_xor(m,off,64));
    if(lane==0) sred[wid][0]=m;
    __syncthreads();
    if(t==0){
      for(int i=1;i<8;i++) m=fmaxf(m,sred[i][0]);
      bsv[8]=fmaxf(m/127.f,1e-8f);
    }
    __syncthreads();
    float s=bsv[8];
    for(int i=bid*512+t;i<BATCH*10;i+=nblk*512)
      out[i]=fminf(fmaxf(rintf(lg[i]/s),-128.f),127.f)*s;
  }
}

extern "C" void kernel_launch(void* const* d_in, const int* in_sizes, int n_in,
                              void* d_out, int out_size, void* d_ws, size_t ws_size,
                              hipStream_t stream){
  const float* img=(const float*)d_in[0];
  const float* W1 =(const float*)d_in[1];
  const float* b1 =(const float*)d_in[2];
  const float* Wc =(const float*)d_in[3];
  const float* bc =(const float*)d_in[4];
  const float* Wf =(const float*)d_in[5];
  const float* bf =(const float*)d_in[6];
  float* out=(float*)d_out;
  char* wsb=(char*)d_ws;

  int nblk=512;
  int maxb=0;
  if(hipOccupancyMaxActiveBlocksPerMultiprocessor(&maxb,k_mega,512,0)==hipSuccess && maxb>0){
    int dev=0; hipGetDevice(&dev);
    int cus=0;
    if(hipDeviceGetAttribute(&cus,hipDeviceAttributeMultiprocessorCount,dev)==hipSuccess && cus>0){
      int cap=maxb*cus;
      if(cap<nblk) nblk=cap;
    }
  } else {
    nblk=256;   // conservative fallback: 1 block/CU fits easily
  }

  void* args[]={(void*)&img,(void*)&W1,(void*)&b1,(void*)&Wc,(void*)&bc,
                (void*)&Wf,(void*)&bf,(void*)&out,(void*)&wsb,(void*)&nblk};
  hipLaunchCooperativeKernel((void*)k_mega,dim3(nblk),dim3(512),args,0,stream);
}

// Round 18
// 102.262 us; speedup vs baseline: 2.5416x; 2.5416x over previous
//
#include <hip/hip_runtime.h>

#define BATCH 4096
#define MD 384
#define KW 15
#define LSEQ 28
#define FIN 28
#define NX (BATCH*LSEQ*FIN)
#define NROWS (BATCH*LSEQ)

// scf slots: 0 s_img, 1 s_w1, 2 s_wc, 3 s_wf, 4 s_lin, 5 s_o1, 6 s_cv, 7 s_o2
// workspace layout (byte offsets, 16B-aligned)
#define B_SCF  0
#define B_LUT1 256
#define B_LUT2 512
#define B_PT0  1024      // 2048 float4
#define B_PT1  33792     // 1024 float2
#define B_PT2  50176     // 1024 float2
#define B_PTL  66560     // 1024 float
#define B_W1B  74752     // MD*32 bf16 = 24576
#define B_WCQ  99328     // MD*16 i8 = 6144
#define B_WFB  105472    // 16*10752 i8 = 172032 (rows 10..15 pad)
#define B_LG   277504    // 40960 float
#define B_XQB  441344    // NROWS*32 bf16 = 7340032 -> 7781376
#define B_CWG  7781376   // 1024 blocks * 10752 ints = 44040192 B

typedef __bf16 bf16x8 __attribute__((ext_vector_type(8)));
typedef float f32x4 __attribute__((ext_vector_type(4)));
typedef int i32x4 __attribute__((ext_vector_type(4)));

#if __has_builtin(__builtin_amdgcn_sdot4)
#define SDOT4(a,b,c) __builtin_amdgcn_sdot4((a),(b),(c),false)
#else
__device__ __forceinline__ int SDOT4(int a,int b,int c){
  c += ((a<<24)>>24)*((b<<24)>>24);
  c += ((a<<16)>>24)*((b<<16)>>24);
  c += ((a<<8)>>24)*((b<<8)>>24);
  c += (a>>24)*(b>>24);
  return c;
}
#endif

#if __has_builtin(__builtin_amdgcn_alignbyte)
#define ALIGNB(hi,lo,s) __builtin_amdgcn_alignbyte((hi),(lo),(s))
#else
#define ALIGNB(hi,lo,s) ((int)(((unsigned)(lo)>>(8*(s)))|((unsigned)(hi)<<(32-8*(s)))))
#endif

__device__ __forceinline__ unsigned short f2bf(float f){
  return (unsigned short)(__float_as_uint(f)>>16);   // exact for small ints
}
__device__ __forceinline__ unsigned lut_bperm(int iw,int lutw){
  int res=__builtin_amdgcn_ds_bpermute(iw,lutw);    // lane = iw>>2
  return ((unsigned)res>>(8*(iw&3)))&0xFFu;
}

__device__ __forceinline__ void blkStore4(float m0,float m1,float m2,float m3,float4* dst){
  #pragma unroll
  for(int off=32;off;off>>=1){
    m0=fmaxf(m0,__shfl_xor(m0,off,64));
    m1=fmaxf(m1,__shfl_xor(m1,off,64));
    m2=fmaxf(m2,__shfl_xor(m2,off,64));
    m3=fmaxf(m3,__shfl_xor(m3,off,64));
  }
  __shared__ float sm[4][4];
  int wid=threadIdx.x>>6;
  if((threadIdx.x&63)==0){sm[wid][0]=m0;sm[wid][1]=m1;sm[wid][2]=m2;sm[wid][3]=m3;}
  __syncthreads();
  if(threadIdx.x==0){
    for(int i=1;i<4;i++){
      m0=fmaxf(m0,sm[i][0]);m1=fmaxf(m1,sm[i][1]);
      m2=fmaxf(m2,sm[i][2]);m3=fmaxf(m3,sm[i][3]);
    }
    *dst=make_float4(m0,m1,m2,m3);
  }
}

__device__ __forceinline__ void blkStoreMM(float mn,float mx,float2* dst){
  #pragma unroll
  for(int off=32;off;off>>=1){
    mn=fminf(mn,__shfl_xor(mn,off,64));
    mx=fmaxf(mx,__shfl_xor(mx,off,64));
  }
  __shared__ float smn[8],smx[8];
  int wid=threadIdx.x>>6, nw=blockDim.x>>6;
  if((threadIdx.x&63)==0){smn[wid]=mn;smx[wid]=mx;}
  __syncthreads();
  if(threadIdx.x==0){
    for(int i=1;i<nw;i++){mn=fminf(mn,smn[i]);mx=fmaxf(mx,smx[i]);}
    *dst=make_float2(mn,mx);
  }
}

// ---------- kernels ----------
__global__ __launch_bounds__(256)
void k_maxabs_in(const float* __restrict__ img,const float* __restrict__ W1,
                 const float* __restrict__ Wc,const float* __restrict__ Wf,
                 float4* __restrict__ pt0){
  float m0=0.f,m1=0.f,m2=0.f,m3=0.f;
  const int N4=NX/4;
  const int NW1=MD*FIN, NWC=MD*KW, NWF=10*MD*LSEQ;
  const int total=N4+NW1+NWC+NWF;
  const float4* img4=(const float4*)img;
  for(int i=blockIdx.x*blockDim.x+threadIdx.x;i<total;i+=gridDim.x*blockDim.x){
    if(i<N4){
      float4 v=img4[i];
      m0=fmaxf(m0,fmaxf(fmaxf(fabsf(v.x),fabsf(v.y)),fmaxf(fabsf(v.z),fabsf(v.w))));
    }
    else if(i<N4+NW1) m1=fmaxf(m1,fabsf(W1[i-N4]));
    else if(i<N4+NW1+NWC) m2=fmaxf(m2,fabsf(Wc[i-N4-NW1]));
    else m3=fmaxf(m3,fabsf(Wf[i-N4-NW1-NWC]));
  }
  blkStore4(m0,m1,m2,m3,&pt0[blockIdx.x]);
}

__global__ __launch_bounds__(256)
void k_red0(const float4* __restrict__ pt,float* __restrict__ scf){
  int t=threadIdx.x;
  float m0=0.f,m1=0.f,m2=0.f,m3=0.f;
  for(int i=t;i<2048;i+=256){
    float4 v=pt[i];
    m0=fmaxf(m0,v.x);m1=fmaxf(m1,v.y);m2=fmaxf(m2,v.z);m3=fmaxf(m3,v.w);
  }
  #pragma unroll
  for(int off=32;off;off>>=1){
    m0=fmaxf(m0,__shfl_xor(m0,off,64));
    m1=fmaxf(m1,__shfl_xor(m1,off,64));
    m2=fmaxf(m2,__shfl_xor(m2,off,64));
    m3=fmaxf(m3,__shfl_xor(m3,off,64));
  }
  __shared__ float sm[4][4];
  int wid=t>>6;
  if((t&63)==0){sm[wid][0]=m0;sm[wid][1]=m1;sm[wid][2]=m2;sm[wid][3]=m3;}
  __syncthreads();
  if(t==0){
    for(int i=1;i<4;i++){
      m0=fmaxf(m0,sm[i][0]);m1=fmaxf(m1,sm[i][1]);
      m2=fmaxf(m2,sm[i][2]);m3=fmaxf(m3,sm[i][3]);
    }
    scf[0]=fmaxf(m0/127.f,1e-8f);
    scf[1]=fmaxf(m1/3.f,1e-8f);
    scf[2]=fmaxf(m2/3.f,1e-8f);
    scf[3]=fmaxf(m3/3.f,1e-8f);
  }
}

__global__ __launch_bounds__(256)
void k_redmm(const float2* __restrict__ pt,int n,float* __restrict__ scf,
             int preIdx,int outIdx,char* __restrict__ lutg){
  int t=threadIdx.x;
  float mn=1e30f,mx=-1e30f;
  for(int i=t;i<n;i+=256){
    float2 v=pt[i];
    mn=fminf(mn,v.x); mx=fmaxf(mx,v.y);
  }
  #pragma unroll
  for(int off=32;off;off>>=1){
    mn=fminf(mn,__shfl_xor(mn,off,64));
    mx=fmaxf(mx,__shfl_xor(mx,off,64));
  }
  __shared__ float smn[4],smx[4];
  __shared__ float bs,bso;
  int wid=t>>6;
  if((t&63)==0){smn[wid]=mn;smx[wid]=mx;}
  __syncthreads();
  if(t==0){
    for(int i=1;i<4;i++){mn=fminf(mn,smn[i]);mx=fmaxf(mx,smx[i]);}
    float ma=fmaxf(fabsf(mn),fabsf(mx));
    float s=fmaxf(ma/127.f,1e-8f);
    float a1=fabsf(fminf(fmaxf(rintf(mn/s),-128.f),127.f)*s);
    float a2=fabsf(fminf(fmaxf(rintf(mx/s),-128.f),127.f)*s);
    float so=fmaxf(tanhf(fmaxf(a1,a2))/127.f,1e-8f);
    scf[preIdx]=s; scf[outIdx]=so;
    bs=s; bso=so;
  }
  __syncthreads();
  float d=(float)(t-128)*bs;
  lutg[t]=(char)(int)fminf(fmaxf(rintf(tanhf(d)/bso),-128.f),127.f);
}

// quantize inputs into code tensors
__global__ __launch_bounds__(256)
void k_prep(const float* __restrict__ img,const float* __restrict__ W1,
            const float* __restrict__ Wc,const float* __restrict__ Wf,
            const float* __restrict__ scf,char* __restrict__ wsb){
  float s_img=scf[0], s_w1=scf[1], s_wc=scf[2], s_wf=scf[3];
  float inv_img=1.f/s_img;
  unsigned short* xqb=(unsigned short*)(wsb+B_XQB);
  unsigned short* w1b=(unsigned short*)(wsb+B_W1B);
  char* wcpk=wsb+B_WCQ;
  char* wfb=wsb+B_WFB;
  const int T0=NROWS*32;
  const int T1=T0+MD*32;
  const int T2=T1+MD*16;
  const int T3=T2+10*10752;
  for(int i=blockIdx.x*blockDim.x+threadIdx.x;i<T3;i+=gridDim.x*blockDim.x){
    if(i<T0){
      int row=i>>5, cc=i&31;
      float q = cc<FIN ? fminf(fmaxf(rintf(img[row*FIN+cc]*inv_img),-128.f),127.f) : 0.f;
      xqb[i]=f2bf(q);
    } else if(i<T1){
      int j=i-T0; int o=j>>5, cc=j&31;
      float q = cc<FIN ? fminf(fmaxf(rintf(W1[o*FIN+cc]/s_w1),-4.f),3.f) : 0.f;
      w1b[j]=f2bf(q);
    } else if(i<T2){
      int j=i-T1; int c=j>>4, k=j&15;
      char q=0;
      if(k<KW) q=(char)(int)fminf(fmaxf(rintf(Wc[c*KW+k]/s_wc),-4.f),3.f);
      wcpk[j]=q;
    } else {
      int j=i-T2;                 // wfb[n][c*28+l]
      int n=j/10752, r=j-n*10752;
      int c=r/28, l=r-c*28;
      wfb[j]=(char)(int)fminf(fmaxf(rintf(Wf[n*10752+l*MD+c]/s_wf),-4.f),3.f);
    }
  }
}

// Fused block = 4 samples (112 rows x 384 o), 1024 blocks, 512 threads.
// MODE 0: lin minmax -> pt1. MODE 1: lin codes (dumped to cwg) -> conv minmax -> pt2.
// MODE 2: conv reads cwg DIRECT (global, coalesced rows) -> Dw in LDS -> i8-MFMA
//         gemm2 -> logits + max partial.
#define CWS 29          // padded Cw row stride (ints), coprime with 32
#define DWS 2692        // Dw sample stride in INTS (2688 data + 4 pad) = 10768 B
template<int MODE>
__global__ __launch_bounds__(512)
void k_fused(const unsigned short* __restrict__ xqb,const unsigned short* __restrict__ w1b,
             const float* __restrict__ b1,const float* __restrict__ scf,
             const char* __restrict__ lut1g,const char* __restrict__ lut2g,
             const char* __restrict__ wcpk,const float* __restrict__ bc,
             const char* __restrict__ wfb,const float* __restrict__ bfv,
             int* __restrict__ cwg,
             float2* __restrict__ ptmm,float* __restrict__ lg,
             float* __restrict__ ptl){
  __shared__ int ldsI[MD*CWS];         // W1 stage -> Cw[384][29]; MODE2: Dw only
  __shared__ int psumN[8][10][4];
  int t=threadIdx.x, wid=t>>6, lane=t&63, l4=lane>>4, l15=lane&15;

  bf16x8 bfr[3]; float b1v[3]; bf16x8 af[7];
  if constexpr(MODE<2){
    const int* src=(const int*)w1b;
    for(int i=t;i<6144;i+=512) ldsI[i]=src[i];
    __syncthreads();
    unsigned short* Wlds=(unsigned short*)ldsI;
    #pragma unroll
    for(int ni=0;ni<3;ni++){
      int o=(wid*3+ni)*16+l15;
      bfr[ni]=*(const bf16x8*)&Wlds[o*32+l4*8];
      b1v[ni]=b1[o];
    }
    int r0=blockIdx.x*112;
    #pragma unroll
    for(int mt=0;mt<7;mt++)
      af[mt]=*(const bf16x8*)&xqb[(size_t)(r0+mt*16+l15)*32+l4*8];
  }

  float sg=scf[0]*scf[1];
  float sgi=sg, b1s[3]={0.f,0.f,0.f};
  int lutA_w=0,lutB_w=0;
  float ck1=1.f,inv_cv=1.f,sfac=1.f,gsc=1.f;
  if constexpr(MODE>=1){
    sfac=scf[5]*scf[2];                 // s_o1 * s_wc
  }
  if constexpr(MODE==1){
    float inv_lin=1.f/scf[4];
    sgi=sg*inv_lin;
    #pragma unroll
    for(int ni=0;ni<3;ni++) b1s[ni]=fmaf(b1v[ni],inv_lin,128.f);
    lutA_w=((const int*)lut1g)[lane];
    __syncthreads();                    // Wlds frag reads done before Cw overwrite
  }
  if constexpr(MODE==2){
    inv_cv=1.f/scf[6];
    ck1=sfac*inv_cv;                    // idot -> quant domain
    gsc=scf[3]*scf[7];                  // s_wf * s_o2
    lutB_w=((const int*)lut2g)[lane];
  }

  if constexpr(MODE<2){
    f32x4 zero={0.f,0.f,0.f,0.f};
    float mnn[3]={1e30f,1e30f,1e30f},mxx[3]={-1e30f,-1e30f,-1e30f};
    #pragma unroll
    for(int ni=0;ni<3;ni++){
      int o=(wid*3+ni)*16+l15;
      #pragma unroll
      for(int mt=0;mt<7;mt++){
        f32x4 acc=__builtin_amdgcn_mfma_f32_16x16x32_bf16(af[mt],bfr[ni],zero,0,0,0);
        if constexpr(MODE==0){
          #pragma unroll
          for(int r=0;r<4;r++){
            mnn[ni]=fminf(mnn[ni],acc[r]); mxx[ni]=fmaxf(mxx[ni],acc[r]);
          }
        } else {
          unsigned w=0;
          #pragma unroll
          for(int r=0;r<4;r++){
            float x=fmaf(acc[r],sgi,b1s[ni]);   // quant domain, biased +128
            int iw=(int)__builtin_amdgcn_fmed3f(rintf(x),0.f,255.f);
            w|=lut_bperm(iw,lutA_w)<<(8*r);
          }
          ldsI[o*CWS+mt*4+l4]=(int)w;
        }
      }
    }
    if constexpr(MODE==0){
      float mn=1e30f,mx=-1e30f;
      #pragma unroll
      for(int ni=0;ni<3;ni++){
        mn=fminf(mn,fmaf(mnn[ni],sg,b1v[ni]));
        mx=fmaxf(mx,fmaf(mxx[ni],sg,b1v[ni]));
      }
      blkStoreMM(mn,mx,&ptmm[blockIdx.x]);
      return;
    }
    __syncthreads();                     // Cw complete
    // MODE 1: dump Cw codes to global (coalesced int4); read-only on ldsI
    {
      int4* dst=(int4*)(cwg+(size_t)blockIdx.x*10752);
      for(int jj=t;jj<2688;jj+=512){
        int j=jj*4, o=j/28, idx=j-o*28, base=o*CWS+idx;
        int4 v; v.x=ldsI[base]; v.y=ldsI[base+1]; v.z=ldsI[base+2]; v.w=ldsI[base+3];
        dst[jj]=v;
      }
    }
  }

  // depthwise conv: 1536 rows (s,c), 3 per thread.
  // MODE 1 reads Cw from LDS. MODE 2 reads rows DIRECT from cwg (L2-warm).
  float mnc=1e30f,mxc=-1e30f;
  unsigned oww[3][7];
  #pragma unroll
  for(int rr=0;rr<3;rr++){
    int j=t+rr*512;
    int s=j/384, c=j-s*384;
    i32x4 wq=*(const i32x4*)(wcpk+(size_t)c*16);
    float cbias=bc[c];
    float cq2=0.f;
    if constexpr(MODE==2) cq2=fmaf(cbias,inv_cv,128.f);
    int ext[11];
    ext[0]=0; ext[1]=0; ext[9]=0; ext[10]=0;
    if constexpr(MODE==1){
      #pragma unroll
      for(int i=0;i<7;i++) ext[2+i]=ldsI[c*CWS+s*7+i];
    } else {
      const int* row=cwg+(size_t)blockIdx.x*10752+(size_t)(c*28)+s*7;
      #pragma unroll
      for(int i=0;i<7;i++) ext[2+i]=row[i];
    }
    int imn=0x7FFFFFFF,imx=0x80000000;
    #pragma unroll
    for(int l=0;l<LSEQ;l++){
      const int eb=l+1, bi=eb>>2, sh=eb&3;
      int A0,A1,A2,A3;
      if(sh==0){A0=ext[bi];A1=ext[bi+1];A2=ext[bi+2];A3=ext[bi+3];}
      else{
        A0=ALIGNB(ext[bi+1],ext[bi],sh);
        A1=ALIGNB(ext[bi+2],ext[bi+1],sh);
        A2=ALIGNB(ext[bi+3],ext[bi+2],sh);
        A3=ALIGNB(ext[bi+4],ext[bi+3],sh);
      }
      int idot=SDOT4(A0,wq[0],SDOT4(A1,wq[1],SDOT4(A2,wq[2],SDOT4(A3,wq[3],0))));
      if constexpr(MODE==1){
        imn=min(imn,idot); imx=max(imx,idot);
      } else {
        float x=fmaf((float)idot,ck1,cq2);
        int iw=(int)__builtin_amdgcn_fmed3f(rintf(x),0.f,255.f);
        unsigned q2=lut_bperm(iw,lutB_w);
        if((l&3)==0) oww[rr][l>>2]=q2;
        else oww[rr][l>>2]|=q2<<(8*(l&3));
      }
    }
    if constexpr(MODE==1){
      mnc=fminf(mnc,fmaf((float)imn,sfac,cbias));
      mxc=fmaxf(mxc,fmaf((float)imx,sfac,cbias));
    }
  }
  if constexpr(MODE==1){
    blkStoreMM(mnc,mxc,&ptmm[blockIdx.x]);
    return;
  }

  // MODE 2: write conv codes sample-major Dw[s*DWS + c*7 + i] (no prior LDS use)
  #pragma unroll
  for(int rr=0;rr<3;rr++){
    int j=t+rr*512;
    int s=j/384, c=j-s*384;
    #pragma unroll
    for(int i=0;i<7;i++) ldsI[s*DWS+c*7+i]=(int)oww[rr][i];
  }
  __syncthreads();

  // in-block gemm2 via i8 MFMA. K = 10752 B = 168 k-blocks of 64; 21/wave,
  // two independent accumulator chains.
  {
    i32x4 acc0={0,0,0,0}, acc1={0,0,0,0};
    const char* ldsB=(const char*)ldsI;
    for(int kb=wid;kb<168;kb+=16){
      i32x4 a=*(const i32x4*)(ldsB+(size_t)(l15&3)*(DWS*4)+kb*64+l4*16);
      i32x4 b=*(const i32x4*)(wfb+(size_t)l15*10752+kb*64+l4*16);
      acc0=__builtin_amdgcn_mfma_i32_16x16x64_i8(a,b,acc0,0,0,0);
      int kb2=kb+8;
      if(kb2<168){
        i32x4 a2=*(const i32x4*)(ldsB+(size_t)(l15&3)*(DWS*4)+kb2*64+l4*16);
        i32x4 b2=*(const i32x4*)(wfb+(size_t)l15*10752+kb2*64+l4*16);
        acc1=__builtin_amdgcn_mfma_i32_16x16x64_i8(a2,b2,acc1,0,0,0);
      }
    }
    if(l4==0&&l15<10){
      #pragma unroll
      for(int r=0;r<4;r++) psumN[wid][l15][r]=acc0[r]+acc1[r];
    }
  }
  __syncthreads();
  float m=0.f;
  if(t<40){
    int s=t/10, o=t-s*10;
    int sum=0;
    #pragma unroll
    for(int w=0;w<8;w++) sum+=psumN[w][o][s];
    float v=fmaf((float)sum,gsc,bfv[o]);
    lg[(blockIdx.x*4+s)*10+o]=v;
    m=fabsf(v);
  }
  if(t<64){
    #pragma unroll
    for(int off=32;off;off>>=1) m=fmaxf(m,__shfl_xor(m,off,64));
    if(t==0) ptl[blockIdx.x]=m;
  }
}

__global__ __launch_bounds__(256)
void k_final(const float* __restrict__ lg,const float* __restrict__ ptl,
             float* __restrict__ out){
  int t=threadIdx.x;
  float m=0.f;
  for(int i=t;i<1024;i+=256) m=fmaxf(m,ptl[i]);
  #pragma unroll
  for(int off=32;off;off>>=1) m=fmaxf(m,__shfl_xor(m,off,64));
  __shared__ float sm[4];
  __shared__ float sv;
  int wid=t>>6;
  if((t&63)==0) sm[wid]=m;
  __syncthreads();
  if(t==0){
    for(int k=1;k<4;k++) m=fmaxf(m,sm[k]);
    sv=fmaxf(m/127.f,1e-8f);
  }
  __syncthreads();
  float s=sv;
  int i=blockIdx.x*256+t;
  out[i]=fminf(fmaxf(rintf(lg[i]/s),-128.f),127.f)*s;
}

extern "C" void kernel_launch(void* const* d_in, const int* in_sizes, int n_in,
                              void* d_out, int out_size, void* d_ws, size_t ws_size,
                              hipStream_t stream){
  const float* img=(const float*)d_in[0];
  const float* W1 =(const float*)d_in[1];
  const float* b1 =(const float*)d_in[2];
  const float* Wc =(const float*)d_in[3];
  const float* bc =(const float*)d_in[4];
  const float* Wf =(const float*)d_in[5];
  const float* bf =(const float*)d_in[6];
  float* out=(float*)d_out;
  char* wsb=(char*)d_ws;
  float* scf=(float*)(wsb+B_SCF);
  float4* pt0=(float4*)(wsb+B_PT0);
  float2* pt1=(float2*)(wsb+B_PT1);
  float2* pt2=(float2*)(wsb+B_PT2);
  float* ptl=(float*)(wsb+B_PTL);
  float* lg=(float*)(wsb+B_LG);
  int* cwg=(int*)(wsb+B_CWG);
  const unsigned short* xqb=(const unsigned short*)(wsb+B_XQB);
  const unsigned short* w1b=(const unsigned short*)(wsb+B_W1B);
  const char* wcpk=wsb+B_WCQ;
  const char* wfb=wsb+B_WFB;

  k_maxabs_in<<<2048,256,0,stream>>>(img,W1,Wc,Wf,pt0);
  k_red0<<<1,256,0,stream>>>(pt0,scf);
  k_prep<<<4096,256,0,stream>>>(img,W1,Wc,Wf,scf,wsb);
  k_fused<0><<<1024,512,0,stream>>>(xqb,w1b,b1,scf,nullptr,nullptr,wcpk,bc,wfb,bf,cwg,pt1,nullptr,nullptr);
  k_redmm<<<1,256,0,stream>>>(pt1,1024,scf,4,5,wsb+B_LUT1);
  k_fused<1><<<1024,512,0,stream>>>(xqb,w1b,b1,scf,wsb+B_LUT1,nullptr,wcpk,bc,wfb,bf,cwg,pt2,nullptr,nullptr);
  k_redmm<<<1,256,0,stream>>>(pt2,1024,scf,6,7,wsb+B_LUT2);
  k_fused<2><<<1024,512,0,stream>>>(xqb,w1b,b1,scf,wsb+B_LUT1,wsb+B_LUT2,wcpk,bc,wfb,bf,cwg,nullptr,lg,ptl);
  k_final<<<160,256,0,stream>>>(lg,ptl,out);
}

// Round 19
// 101.545 us; speedup vs baseline: 2.5595x; 1.0071x over previous
//
#include <hip/hip_runtime.h>

#define BATCH 4096
#define MD 384
#define KW 15
#define LSEQ 28
#define FIN 28
#define NX (BATCH*LSEQ*FIN)
#define NROWS (BATCH*LSEQ)

// scf slots: 0 s_img, 1 s_w1, 2 s_wc, 3 s_wf, 4 s_lin, 5 s_o1, 6 s_cv, 7 s_o2
// workspace layout (byte offsets, 16B-aligned)
#define B_SCF  0
#define B_LUT1 256
#define B_LUT2 512
#define B_PT0  1024      // 2048 float4
#define B_PT1  33792     // 1024 float2
#define B_PT2  50176     // 1024 float2
#define B_PTL  66560     // 1024 float
#define B_W1B  74752     // MD*32 bf16 = 24576
#define B_WCQ  99328     // MD*16 i8 = 6144
#define B_WFB  105472    // 16*10752 i8 = 172032 (rows 10..15 pad)
#define B_LG   277504    // 40960 float
#define B_XQB  441344    // NROWS*32 bf16 = 7340032 -> 7781376
#define B_CWG  7781376   // 1024 blocks * 10752 ints = 44040192 B

typedef __bf16 bf16x8 __attribute__((ext_vector_type(8)));
typedef float f32x4 __attribute__((ext_vector_type(4)));
typedef int i32x4 __attribute__((ext_vector_type(4)));

#if __has_builtin(__builtin_amdgcn_sdot4)
#define SDOT4(a,b,c) __builtin_amdgcn_sdot4((a),(b),(c),false)
#else
__device__ __forceinline__ int SDOT4(int a,int b,int c){
  c += ((a<<24)>>24)*((b<<24)>>24);
  c += ((a<<16)>>24)*((b<<16)>>24);
  c += ((a<<8)>>24)*((b<<8)>>24);
  c += (a>>24)*(b>>24);
  return c;
}
#endif

#if __has_builtin(__builtin_amdgcn_alignbyte)
#define ALIGNB(hi,lo,s) __builtin_amdgcn_alignbyte((hi),(lo),(s))
#else
#define ALIGNB(hi,lo,s) ((int)(((unsigned)(lo)>>(8*(s)))|((unsigned)(hi)<<(32-8*(s)))))
#endif

// fusable 3-input min/max (clang emits v_min3_f32 / v_max3_f32)
#define MIN3(a,b,c) fminf(fminf((a),(b)),(c))
#define MAX3(a,b,c) fmaxf(fmaxf((a),(b)),(c))

__device__ __forceinline__ unsigned short f2bf(float f){
  return (unsigned short)(__float_as_uint(f)>>16);   // exact for small ints
}
__device__ __forceinline__ unsigned lut_bperm(int iw,int lutw){
  int res=__builtin_amdgcn_ds_bpermute(iw,lutw);    // lane = iw>>2
  return ((unsigned)res>>(8*(iw&3)))&0xFFu;
}

__device__ __forceinline__ void blkStore4(float m0,float m1,float m2,float m3,float4* dst){
  #pragma unroll
  for(int off=32;off;off>>=1){
    m0=fmaxf(m0,__shfl_xor(m0,off,64));
    m1=fmaxf(m1,__shfl_xor(m1,off,64));
    m2=fmaxf(m2,__shfl_xor(m2,off,64));
    m3=fmaxf(m3,__shfl_xor(m3,off,64));
  }
  __shared__ float sm[4][4];
  int wid=threadIdx.x>>6;
  if((threadIdx.x&63)==0){sm[wid][0]=m0;sm[wid][1]=m1;sm[wid][2]=m2;sm[wid][3]=m3;}
  __syncthreads();
  if(threadIdx.x==0){
    for(int i=1;i<4;i++){
      m0=fmaxf(m0,sm[i][0]);m1=fmaxf(m1,sm[i][1]);
      m2=fmaxf(m2,sm[i][2]);m3=fmaxf(m3,sm[i][3]);
    }
    *dst=make_float4(m0,m1,m2,m3);
  }
}

__device__ __forceinline__ void blkStoreMM(float mn,float mx,float2* dst){
  #pragma unroll
  for(int off=32;off;off>>=1){
    mn=fminf(mn,__shfl_xor(mn,off,64));
    mx=fmaxf(mx,__shfl_xor(mx,off,64));
  }
  __shared__ float smn[8],smx[8];
  int wid=threadIdx.x>>6, nw=blockDim.x>>6;
  if((threadIdx.x&63)==0){smn[wid]=mn;smx[wid]=mx;}
  __syncthreads();
  if(threadIdx.x==0){
    for(int i=1;i<nw;i++){mn=fminf(mn,smn[i]);mx=fmaxf(mx,smx[i]);}
    *dst=make_float2(mn,mx);
  }
}

// ---------- kernels ----------
__global__ __launch_bounds__(256)
void k_maxabs_in(const float* __restrict__ img,const float* __restrict__ W1,
                 const float* __restrict__ Wc,const float* __restrict__ Wf,
                 float4* __restrict__ pt0){
  float m0=0.f,m1=0.f,m2=0.f,m3=0.f;
  const int N4=NX/4;
  const int NW1=MD*FIN, NWC=MD*KW, NWF=10*MD*LSEQ;
  const int total=N4+NW1+NWC+NWF;
  const float4* img4=(const float4*)img;
  for(int i=blockIdx.x*blockDim.x+threadIdx.x;i<total;i+=gridDim.x*blockDim.x){
    if(i<N4){
      float4 v=img4[i];
      m0=fmaxf(m0,fmaxf(fmaxf(fabsf(v.x),fabsf(v.y)),fmaxf(fabsf(v.z),fabsf(v.w))));
    }
    else if(i<N4+NW1) m1=fmaxf(m1,fabsf(W1[i-N4]));
    else if(i<N4+NW1+NWC) m2=fmaxf(m2,fabsf(Wc[i-N4-NW1]));
    else m3=fmaxf(m3,fabsf(Wf[i-N4-NW1-NWC]));
  }
  blkStore4(m0,m1,m2,m3,&pt0[blockIdx.x]);
}

__global__ __launch_bounds__(256)
void k_red0(const float4* __restrict__ pt,float* __restrict__ scf){
  int t=threadIdx.x;
  float m0=0.f,m1=0.f,m2=0.f,m3=0.f;
  for(int i=t;i<2048;i+=256){
    float4 v=pt[i];
    m0=fmaxf(m0,v.x);m1=fmaxf(m1,v.y);m2=fmaxf(m2,v.z);m3=fmaxf(m3,v.w);
  }
  #pragma unroll
  for(int off=32;off;off>>=1){
    m0=fmaxf(m0,__shfl_xor(m0,off,64));
    m1=fmaxf(m1,__shfl_xor(m1,off,64));
    m2=fmaxf(m2,__shfl_xor(m2,off,64));
    m3=fmaxf(m3,__shfl_xor(m3,off,64));
  }
  __shared__ float sm[4][4];
  int wid=t>>6;
  if((t&63)==0){sm[wid][0]=m0;sm[wid][1]=m1;sm[wid][2]=m2;sm[wid][3]=m3;}
  __syncthreads();
  if(t==0){
    for(int i=1;i<4;i++){
      m0=fmaxf(m0,sm[i][0]);m1=fmaxf(m1,sm[i][1]);
      m2=fmaxf(m2,sm[i][2]);m3=fmaxf(m3,sm[i][3]);
    }
    scf[0]=fmaxf(m0/127.f,1e-8f);
    scf[1]=fmaxf(m1/3.f,1e-8f);
    scf[2]=fmaxf(m2/3.f,1e-8f);
    scf[3]=fmaxf(m3/3.f,1e-8f);
  }
}

__global__ __launch_bounds__(256)
void k_redmm(const float2* __restrict__ pt,int n,float* __restrict__ scf,
             int preIdx,int outIdx,char* __restrict__ lutg){
  int t=threadIdx.x;
  float mn=1e30f,mx=-1e30f;
  for(int i=t;i<n;i+=256){
    float2 v=pt[i];
    mn=fminf(mn,v.x); mx=fmaxf(mx,v.y);
  }
  #pragma unroll
  for(int off=32;off;off>>=1){
    mn=fminf(mn,__shfl_xor(mn,off,64));
    mx=fmaxf(mx,__shfl_xor(mx,off,64));
  }
  __shared__ float smn[4],smx[4];
  __shared__ float bs,bso;
  int wid=t>>6;
  if((t&63)==0){smn[wid]=mn;smx[wid]=mx;}
  __syncthreads();
  if(t==0){
    for(int i=1;i<4;i++){mn=fminf(mn,smn[i]);mx=fmaxf(mx,smx[i]);}
    float ma=fmaxf(fabsf(mn),fabsf(mx));
    float s=fmaxf(ma/127.f,1e-8f);
    float a1=fabsf(fminf(fmaxf(rintf(mn/s),-128.f),127.f)*s);
    float a2=fabsf(fminf(fmaxf(rintf(mx/s),-128.f),127.f)*s);
    float so=fmaxf(tanhf(fmaxf(a1,a2))/127.f,1e-8f);
    scf[preIdx]=s; scf[outIdx]=so;
    bs=s; bso=so;
  }
  __syncthreads();
  float d=(float)(t-128)*bs;
  lutg[t]=(char)(int)fminf(fmaxf(rintf(tanhf(d)/bso),-128.f),127.f);
}

// quantize inputs into code tensors
__global__ __launch_bounds__(256)
void k_prep(const float* __restrict__ img,const float* __restrict__ W1,
            const float* __restrict__ Wc,const float* __restrict__ Wf,
            const float* __restrict__ scf,char* __restrict__ wsb){
  float s_img=scf[0], s_w1=scf[1], s_wc=scf[2], s_wf=scf[3];
  float inv_img=1.f/s_img;
  unsigned short* xqb=(unsigned short*)(wsb+B_XQB);
  unsigned short* w1b=(unsigned short*)(wsb+B_W1B);
  char* wcpk=wsb+B_WCQ;
  char* wfb=wsb+B_WFB;
  const int T0=NROWS*32;
  const int T1=T0+MD*32;
  const int T2=T1+MD*16;
  const int T3=T2+10*10752;
  for(int i=blockIdx.x*blockDim.x+threadIdx.x;i<T3;i+=gridDim.x*blockDim.x){
    if(i<T0){
      int row=i>>5, cc=i&31;
      float q = cc<FIN ? fminf(fmaxf(rintf(img[row*FIN+cc]*inv_img),-128.f),127.f) : 0.f;
      xqb[i]=f2bf(q);
    } else if(i<T1){
      int j=i-T0; int o=j>>5, cc=j&31;
      float q = cc<FIN ? fminf(fmaxf(rintf(W1[o*FIN+cc]/s_w1),-4.f),3.f) : 0.f;
      w1b[j]=f2bf(q);
    } else if(i<T2){
      int j=i-T1; int c=j>>4, k=j&15;
      char q=0;
      if(k<KW) q=(char)(int)fminf(fmaxf(rintf(Wc[c*KW+k]/s_wc),-4.f),3.f);
      wcpk[j]=q;
    } else {
      int j=i-T2;                 // wfb[n][c*28+l]
      int n=j/10752, r=j-n*10752;
      int c=r/28, l=r-c*28;
      wfb[j]=(char)(int)fminf(fmaxf(rintf(Wf[n*10752+l*MD+c]/s_wf),-4.f),3.f);
    }
  }
}

// Fused block = 4 samples (112 rows x 384 o), 1024 blocks, 512 threads.
// MODE 0: lin minmax -> pt1. MODE 1: lin codes (dumped to cwg) -> conv minmax -> pt2.
// MODE 2: conv reads cwg DIRECT (global, coalesced rows) -> Dw in LDS -> i8-MFMA
//         gemm2 -> logits + max partial.
#define CWS 29          // padded Cw row stride (ints), coprime with 32
#define DWS 2692        // Dw sample stride in INTS (2688 data + 4 pad) = 10768 B
template<int MODE>
__global__ __launch_bounds__(512)
void k_fused(const unsigned short* __restrict__ xqb,const unsigned short* __restrict__ w1b,
             const float* __restrict__ b1,const float* __restrict__ scf,
             const char* __restrict__ lut1g,const char* __restrict__ lut2g,
             const char* __restrict__ wcpk,const float* __restrict__ bc,
             const char* __restrict__ wfb,const float* __restrict__ bfv,
             int* __restrict__ cwg,
             float2* __restrict__ ptmm,float* __restrict__ lg,
             float* __restrict__ ptl){
  __shared__ int ldsI[MD*CWS];         // W1 stage -> Cw[384][29]; MODE2: Dw only
  __shared__ int psumN[8][10][4];
  int t=threadIdx.x, wid=t>>6, lane=t&63, l4=lane>>4, l15=lane&15;

  bf16x8 bfr[3]; float b1v[3]; bf16x8 af[7];
  if constexpr(MODE<2){
    const int* src=(const int*)w1b;
    for(int i=t;i<6144;i+=512) ldsI[i]=src[i];
    __syncthreads();
    unsigned short* Wlds=(unsigned short*)ldsI;
    #pragma unroll
    for(int ni=0;ni<3;ni++){
      int o=(wid*3+ni)*16+l15;
      bfr[ni]=*(const bf16x8*)&Wlds[o*32+l4*8];
      b1v[ni]=b1[o];
    }
    int r0=blockIdx.x*112;
    #pragma unroll
    for(int mt=0;mt<7;mt++)
      af[mt]=*(const bf16x8*)&xqb[(size_t)(r0+mt*16+l15)*32+l4*8];
  }

  float sg=scf[0]*scf[1];
  float sgi=sg, b1s[3]={0.f,0.f,0.f};
  int lutA_w=0,lutB_w=0;
  float ck1=1.f,inv_cv=1.f,sfac=1.f,gsc=1.f;
  if constexpr(MODE>=1){
    sfac=scf[5]*scf[2];                 // s_o1 * s_wc
  }
  if constexpr(MODE==1){
    float inv_lin=1.f/scf[4];
    sgi=sg*inv_lin;
    #pragma unroll
    for(int ni=0;ni<3;ni++) b1s[ni]=fmaf(b1v[ni],inv_lin,128.f);
    lutA_w=((const int*)lut1g)[lane];
    __syncthreads();                    // Wlds frag reads done before Cw overwrite
  }
  if constexpr(MODE==2){
    inv_cv=1.f/scf[6];
    ck1=sfac*inv_cv;                    // idot -> quant domain
    gsc=scf[3]*scf[7];                  // s_wf * s_o2
    lutB_w=((const int*)lut2g)[lane];
  }

  if constexpr(MODE<2){
    f32x4 zero={0.f,0.f,0.f,0.f};
    float mnn[3]={1e30f,1e30f,1e30f},mxx[3]={-1e30f,-1e30f,-1e30f};
    #pragma unroll
    for(int ni=0;ni<3;ni++){
      int o=(wid*3+ni)*16+l15;
      #pragma unroll
      for(int mt=0;mt<7;mt++){
        f32x4 acc=__builtin_amdgcn_mfma_f32_16x16x32_bf16(af[mt],bfr[ni],zero,0,0,0);
        if constexpr(MODE==0){
          // fusable min3/max3 triples: 4 instrs instead of 8
          float tn=MIN3(acc[0],acc[1],acc[2]);
          mnn[ni]=MIN3(mnn[ni],tn,acc[3]);
          float tx=MAX3(acc[0],acc[1],acc[2]);
          mxx[ni]=MAX3(mxx[ni],tx,acc[3]);
        } else {
          unsigned w=0;
          #pragma unroll
          for(int r=0;r<4;r++){
            float x=fmaf(acc[r],sgi,b1s[ni]);   // quant domain, biased +128
            int iw=(int)__builtin_amdgcn_fmed3f(rintf(x),0.f,255.f);
            w|=lut_bperm(iw,lutA_w)<<(8*r);
          }
          ldsI[o*CWS+mt*4+l4]=(int)w;
        }
      }
    }
    if constexpr(MODE==0){
      float mn=1e30f,mx=-1e30f;
      #pragma unroll
      for(int ni=0;ni<3;ni++){
        mn=fminf(mn,fmaf(mnn[ni],sg,b1v[ni]));
        mx=fmaxf(mx,fmaf(mxx[ni],sg,b1v[ni]));
      }
      blkStoreMM(mn,mx,&ptmm[blockIdx.x]);
      return;
    }
    __syncthreads();                     // Cw complete
    // MODE 1: dump Cw codes to global (coalesced int4); read-only on ldsI
    {
      int4* dst=(int4*)(cwg+(size_t)blockIdx.x*10752);
      for(int jj=t;jj<2688;jj+=512){
        int j=jj*4, o=j/28, idx=j-o*28, base=o*CWS+idx;
        int4 v; v.x=ldsI[base]; v.y=ldsI[base+1]; v.z=ldsI[base+2]; v.w=ldsI[base+3];
        dst[jj]=v;
      }
    }
  }

  // depthwise conv: 1536 rows (s,c), 3 per thread.
  // MODE 1 reads Cw from LDS. MODE 2 reads rows DIRECT from cwg (L2-warm).
  float mnc=1e30f,mxc=-1e30f;
  unsigned oww[3][7];
  #pragma unroll
  for(int rr=0;rr<3;rr++){
    int j=t+rr*512;
    int s=j/384, c=j-s*384;
    i32x4 wq=*(const i32x4*)(wcpk+(size_t)c*16);
    float cbias=bc[c];
    float cq2=0.f;
    if constexpr(MODE==2) cq2=fmaf(cbias,inv_cv,128.f);
    int ext[11];
    ext[0]=0; ext[1]=0; ext[9]=0; ext[10]=0;
    if constexpr(MODE==1){
      #pragma unroll
      for(int i=0;i<7;i++) ext[2+i]=ldsI[c*CWS+s*7+i];
    } else {
      const int* row=cwg+(size_t)blockIdx.x*10752+(size_t)(c*28)+s*7;
      #pragma unroll
      for(int i=0;i<7;i++) ext[2+i]=row[i];
    }
    int imn=0x7FFFFFFF,imx=0x80000000;
    #pragma unroll
    for(int l=0;l<LSEQ;l++){
      const int eb=l+1, bi=eb>>2, sh=eb&3;
      int A0,A1,A2,A3;
      if(sh==0){A0=ext[bi];A1=ext[bi+1];A2=ext[bi+2];A3=ext[bi+3];}
      else{
        A0=ALIGNB(ext[bi+1],ext[bi],sh);
        A1=ALIGNB(ext[bi+2],ext[bi+1],sh);
        A2=ALIGNB(ext[bi+3],ext[bi+2],sh);
        A3=ALIGNB(ext[bi+4],ext[bi+3],sh);
      }
      int idot=SDOT4(A0,wq[0],SDOT4(A1,wq[1],SDOT4(A2,wq[2],SDOT4(A3,wq[3],0))));
      if constexpr(MODE==1){
        imn=min(imn,idot); imx=max(imx,idot);
      } else {
        float x=fmaf((float)idot,ck1,cq2);
        int iw=(int)__builtin_amdgcn_fmed3f(rintf(x),0.f,255.f);
        unsigned q2=lut_bperm(iw,lutB_w);
        if((l&3)==0) oww[rr][l>>2]=q2;
        else oww[rr][l>>2]|=q2<<(8*(l&3));
      }
    }
    if constexpr(MODE==1){
      mnc=fminf(mnc,fmaf((float)imn,sfac,cbias));
      mxc=fmaxf(mxc,fmaf((float)imx,sfac,cbias));
    }
  }
  if constexpr(MODE==1){
    blkStoreMM(mnc,mxc,&ptmm[blockIdx.x]);
    return;
  }

  // MODE 2: write conv codes sample-major Dw[s*DWS + c*7 + i] (no prior LDS use)
  #pragma unroll
  for(int rr=0;rr<3;rr++){
    int j=t+rr*512;
    int s=j/384, c=j-s*384;
    #pragma unroll
    for(int i=0;i<7;i++) ldsI[s*DWS+c*7+i]=(int)oww[rr][i];
  }
  __syncthreads();

  // in-block gemm2 via i8 MFMA. K = 10752 B = 168 k-blocks of 64; 21/wave,
  // two independent accumulator chains.
  {
    i32x4 acc0={0,0,0,0}, acc1={0,0,0,0};
    const char* ldsB=(const char*)ldsI;
    for(int kb=wid;kb<168;kb+=16){
      i32x4 a=*(const i32x4*)(ldsB+(size_t)(l15&3)*(DWS*4)+kb*64+l4*16);
      i32x4 b=*(const i32x4*)(wfb+(size_t)l15*10752+kb*64+l4*16);
      acc0=__builtin_amdgcn_mfma_i32_16x16x64_i8(a,b,acc0,0,0,0);
      int kb2=kb+8;
      if(kb2<168){
        i32x4 a2=*(const i32x4*)(ldsB+(size_t)(l15&3)*(DWS*4)+kb2*64+l4*16);
        i32x4 b2=*(const i32x4*)(wfb+(size_t)l15*10752+kb2*64+l4*16);
        acc1=__builtin_amdgcn_mfma_i32_16x16x64_i8(a2,b2,acc1,0,0,0);
      }
    }
    if(l4==0&&l15<10){
      #pragma unroll
      for(int r=0;r<4;r++) psumN[wid][l15][r]=acc0[r]+acc1[r];
    }
  }
  __syncthreads();
  float m=0.f;
  if(t<40){
    int s=t/10, o=t-s*10;
    int sum=0;
    #pragma unroll
    for(int w=0;w<8;w++) sum+=psumN[w][o][s];
    float v=fmaf((float)sum,gsc,bfv[o]);
    lg[(blockIdx.x*4+s)*10+o]=v;
    m=fabsf(v);
  }
  if(t<64){
    #pragma unroll
    for(int off=32;off;off>>=1) m=fmaxf(m,__shfl_xor(m,off,64));
    if(t==0) ptl[blockIdx.x]=m;
  }
}

__global__ __launch_bounds__(256)
void k_final(const float* __restrict__ lg,const float* __restrict__ ptl,
             float* __restrict__ out){
  int t=threadIdx.x;
  float m=0.f;
  for(int i=t;i<1024;i+=256) m=fmaxf(m,ptl[i]);
  #pragma unroll
  for(int off=32;off;off>>=1) m=fmaxf(m,__shfl_xor(m,off,64));
  __shared__ float sm[4];
  __shared__ float sv;
  int wid=t>>6;
  if((t&63)==0) sm[wid]=m;
  __syncthreads();
  if(t==0){
    for(int k=1;k<4;k++) m=fmaxf(m,sm[k]);
    sv=fmaxf(m/127.f,1e-8f);
  }
  __syncthreads();
  float s=sv;
  int i=blockIdx.x*256+t;
  out[i]=fminf(fmaxf(rintf(lg[i]/s),-128.f),127.f)*s;
}

extern "C" void kernel_launch(void* const* d_in, const int* in_sizes, int n_in,
                              void* d_out, int out_size, void* d_ws, size_t ws_size,
                              hipStream_t stream){
  const float* img=(const float*)d_in[0];
  const float* W1 =(const float*)d_in[1];
  const float* b1 =(const float*)d_in[2];
  const float* Wc =(const float*)d_in[3];
  const float* bc =(const float*)d_in[4];
  const float* Wf =(const float*)d_in[5];
  const float* bf =(const float*)d_in[6];
  float* out=(float*)d_out;
  char* wsb=(char*)d_ws;
  float* scf=(float*)(wsb+B_SCF);
  float4* pt0=(float4*)(wsb+B_PT0);
  float2* pt1=(float2*)(wsb+B_PT1);
  float2* pt2=(float2*)(wsb+B_PT2);
  float* ptl=(float*)(wsb+B_PTL);
  float* lg=(float*)(wsb+B_LG);
  int* cwg=(int*)(wsb+B_CWG);
  const unsigned short* xqb=(const unsigned short*)(wsb+B_XQB);
  const unsigned short* w1b=(const unsigned short*)(wsb+B_W1B);
  const char* wcpk=wsb+B_WCQ;
  const char* wfb=wsb+B_WFB;

  k_maxabs_in<<<2048,256,0,stream>>>(img,W1,Wc,Wf,pt0);
  k_red0<<<1,256,0,stream>>>(pt0,scf);
  k_prep<<<4096,256,0,stream>>>(img,W1,Wc,Wf,scf,wsb);
  k_fused<0><<<1024,512,0,stream>>>(xqb,w1b,b1,scf,nullptr,nullptr,wcpk,bc,wfb,bf,cwg,pt1,nullptr,nullptr);
  k_redmm<<<1,256,0,stream>>>(pt1,1024,scf,4,5,wsb+B_LUT1);
  k_fused<1><<<1024,512,0,stream>>>(xqb,w1b,b1,scf,wsb+B_LUT1,nullptr,wcpk,bc,wfb,bf,cwg,pt2,nullptr,nullptr);
  k_redmm<<<1,256,0,stream>>>(pt2,1024,scf,6,7,wsb+B_LUT2);
  k_fused<2><<<1024,512,0,stream>>>(xqb,w1b,b1,scf,wsb+B_LUT1,wsb+B_LUT2,wcpk,bc,wfb,bf,cwg,nullptr,lg,ptl);
  k_final<<<160,256,0,stream>>>(lg,ptl,out);
}